// Round 9
// baseline (210.543 us; speedup 1.0000x reference)
//
#include <hip/hip_runtime.h>

// Problem constants (B=16, T=2048, D=512, A=128)
#define NB 16
#define NT 2048
#define ND 512
#define NA 128
#define EPSV 1e-6f
#define SCALE 0.08838834764831845f  // 128^-0.5
#define NCH 4        // s-chunks in attention
#define SCH 512      // s-chunk length

typedef __bf16 bf16;
typedef __bf16 bf16x4 __attribute__((ext_vector_type(4)));
typedef __bf16 bf16x8 __attribute__((ext_vector_type(8)));
typedef float f32x4 __attribute__((ext_vector_type(4)));

// ---------------------------------------------------------------------------
// Kernel 0: build W^T bf16 [256][512]  (rows 0..127 = Wq cols, 128..255 = Wk)
// ---------------------------------------------------------------------------
__global__ void prep_wt(const float* __restrict__ Wq, const float* __restrict__ Wk,
                        bf16* __restrict__ WT) {
    int n = blockIdx.x;
    const float* W = (n < NA) ? Wq : Wk;
    int col = n & (NA - 1);
    for (int k = threadIdx.x; k < ND; k += blockDim.x)
        WT[(size_t)n * ND + k] = (bf16)W[(size_t)k * NA + col];
}

// ---------------------------------------------------------------------------
// Kernel 1: fused norm + V + QK projection GEMM. 16 rows/block, grid 2048.
// ---------------------------------------------------------------------------
__launch_bounds__(256)
__global__ void norm_proj(const float* __restrict__ x, const float* __restrict__ Wv,
                          const float* __restrict__ bvp, const bf16* __restrict__ WT,
                          const float* __restrict__ bq, const float* __restrict__ bk,
                          bf16* __restrict__ QK, float* __restrict__ Vout) {
    __shared__ bf16 xn[16 * ND];  // 16 KB, XOR-swizzled rows
    const int tid = threadIdx.x;
    const int lane = tid & 63, wv = tid >> 6;
    const int row0 = blockIdx.x * 16;

    float wvv[8];
    float sumw = 0.f;
#pragma unroll
    for (int i = 0; i < 4; ++i) { wvv[i]     = Wv[lane * 4 + i];       sumw += wvv[i]; }
#pragma unroll
    for (int i = 0; i < 4; ++i) { wvv[4 + i] = Wv[256 + lane * 4 + i]; sumw += wvv[4 + i]; }
#pragma unroll
    for (int m = 1; m < 64; m <<= 1) sumw += __shfl_xor(sumw, m);
    const float bvs = bvp[0];

#pragma unroll
    for (int r = 0; r < 4; ++r) {
        const int lrow = wv * 4 + r;
        const int grow = row0 + lrow;
        const float* xr = x + (size_t)grow * ND;
        f32x4 a = *(const f32x4*)(xr + lane * 4);
        f32x4 b = *(const f32x4*)(xr + 256 + lane * 4);
        float s = 0.f, sq = 0.f, dw = 0.f;
#pragma unroll
        for (int i = 0; i < 4; ++i) { s += a[i]; sq += a[i] * a[i]; dw += a[i] * wvv[i]; }
#pragma unroll
        for (int i = 0; i < 4; ++i) { s += b[i]; sq += b[i] * b[i]; dw += b[i] * wvv[4 + i]; }
#pragma unroll
        for (int m = 1; m < 64; m <<= 1) {
            s  += __shfl_xor(s, m);
            sq += __shfl_xor(sq, m);
            dw += __shfl_xor(dw, m);
        }
        const float mu  = s * (1.f / 512.f);
        float var = (sq - 512.f * mu * mu) * (1.f / 511.f);
        var = fmaxf(var, 0.f);
        const float inv = 1.f / (sqrtf(var) + EPSV);
        if (lane == 0) Vout[grow] = (dw - mu * sumw) * inv + bvs;

        const int sw = (lrow & 7) << 4;
        bf16x4 v0, v1;
#pragma unroll
        for (int i = 0; i < 4; ++i) v0[i] = (bf16)((a[i] - mu) * inv);
#pragma unroll
        for (int i = 0; i < 4; ++i) v1[i] = (bf16)((b[i] - mu) * inv);
        *(bf16x4*)((char*)xn + lrow * 1024 + ((lane * 8) ^ sw))       = v0;
        *(bf16x4*)((char*)xn + lrow * 1024 + ((512 + lane * 8) ^ sw)) = v1;
    }
    __syncthreads();

    const int c = lane & 15, g = lane >> 4;
    const int asw = (c & 7) << 4;
    f32x4 acc[4];
#pragma unroll
    for (int i = 0; i < 4; ++i) acc[i] = f32x4{0.f, 0.f, 0.f, 0.f};

    for (int ks = 0; ks < 16; ++ks) {
        const bf16x8 af = *(const bf16x8*)((const char*)xn + c * 1024 +
                                           ((ks * 64 + g * 16) ^ asw));
#pragma unroll
        for (int i = 0; i < 4; ++i) {
            const int n = wv * 64 + i * 16 + c;
            const bf16x8 bfr = *(const bf16x8*)(WT + (size_t)n * ND + ks * 32 + g * 8);
            acc[i] = __builtin_amdgcn_mfma_f32_16x16x32_bf16(af, bfr, acc[i], 0, 0, 0);
        }
    }
#pragma unroll
    for (int i = 0; i < 4; ++i) {
        const int n = wv * 64 + i * 16 + c;
        const float bias = (n < NA) ? bq[n] : bk[n - NA];
#pragma unroll
        for (int j = 0; j < 4; ++j)
            QK[(size_t)(row0 + g * 4 + j) * 256 + n] = (bf16)(acc[i][j] + bias);
    }
}

// ---------------------------------------------------------------------------
// Kernel 2: scoreE — single score pass. Computes scores, writes E=exp(s*SCALE)
// as bf16 into the upper half of each out_att row (in-place scratch), and
// accumulates per-chunk partial sums l, w. R4 pass1 structure exactly.
// ---------------------------------------------------------------------------
__launch_bounds__(256)
__global__ void scoreE(const bf16* __restrict__ QK, const float* __restrict__ Vg,
                       float* __restrict__ pl, float* __restrict__ pw,
                       float* __restrict__ out_att) {
    __shared__ bf16 Kt[64 * NA];  // 16 KB, XOR-swizzled
    const int tid = threadIdx.x;
    const int lane = tid & 63, wv = tid >> 6;
    const int b = blockIdx.z, t0 = blockIdx.x * 64, sc = blockIdx.y;
    const int c = lane & 15, g = lane >> 4;
    const int trow = t0 + wv * 16 + c;

    bf16x8 qf[4];
    const bf16* qrow = QK + (size_t)(b * NT + trow) * 256;
#pragma unroll
    for (int ks = 0; ks < 4; ++ks) qf[ks] = *(const bf16x8*)(qrow + ks * 32 + g * 8);

    const int srow = tid >> 4, scc = tid & 15;
    const bf16* kbase = QK + (size_t)(b * NT + sc * SCH + srow) * 256 + NA + scc * 8;
    bf16* kdst = (bf16*)((char*)Kt + srow * 256 + ((scc * 16) ^ ((srow & 7) << 4)));
    bf16x8 sreg[4];

#pragma unroll
    for (int i = 0; i < 4; ++i)
        sreg[i] = *(const bf16x8*)(kbase + (size_t)(i * 16) * 256);

    const float* vbase = Vg + b * NT + sc * SCH;
    // E row scratch: upper 4 KB of this row's out_att space (bf16 index NT + s)
    bf16* erow = (bf16*)(out_att + (size_t)(b * NT + trow) * NT) + NT + sc * SCH;
    float l_loc = 0.f, w_loc = 0.f;

    for (int tt = 0; tt < SCH / 64; ++tt) {
        __syncthreads();
#pragma unroll
        for (int i = 0; i < 4; ++i)
            *(bf16x8*)((char*)kdst + i * 16 * 256) = sreg[i];
        if (tt + 1 < SCH / 64) {
#pragma unroll
            for (int i = 0; i < 4; ++i)
                sreg[i] = *(const bf16x8*)(kbase + (size_t)((tt + 1) * 64 + i * 16) * 256);
        }
        __syncthreads();

#pragma unroll
        for (int ns = 0; ns < 4; ++ns) {
            f32x4 acc = f32x4{0.f, 0.f, 0.f, 0.f};
            const int rr = ns * 16 + c;
            const int rsw = (rr & 7) << 4;
#pragma unroll
            for (int ks = 0; ks < 4; ++ks) {
                const bf16x8 afr = *(const bf16x8*)((const char*)Kt + rr * 256 +
                                                    ((ks * 64 + g * 16) ^ rsw));
                acc = __builtin_amdgcn_mfma_f32_16x16x32_bf16(afr, qf[ks], acc, 0, 0, 0);
            }
            const f32x4 vv = *(const f32x4*)(vbase + tt * 64 + ns * 16 + g * 4);
            bf16x4 ev;
#pragma unroll
            for (int jj = 0; jj < 4; ++jj) {
                const float p = __expf(acc[jj] * SCALE);
                l_loc += p;
                w_loc += p * vv[jj];
                ev[jj] = (bf16)p;
            }
            *(bf16x4*)(erow + tt * 64 + ns * 16 + g * 4) = ev;
        }
    }

    // merge partials across the 4 g-lanes sharing trow
#pragma unroll
    for (int mask = 16; mask <= 32; mask <<= 1) {
        l_loc += __shfl_xor(l_loc, mask);
        w_loc += __shfl_xor(w_loc, mask);
    }
    if (g == 0) {
        const int idx = sc * (NB * NT) + b * NT + trow;
        pl[idx] = l_loc;
        pw[idx] = w_loc;
    }
}

// ---------------------------------------------------------------------------
// Kernel 3: merge the 4 chunk-partials -> 1/l, out_w
// ---------------------------------------------------------------------------
__global__ void attn_reduce(const float* __restrict__ pl, const float* __restrict__ pw,
                            float* __restrict__ linv, float* __restrict__ out_w) {
    const int r = blockIdx.x * 256 + threadIdx.x;  // 0 .. NB*NT-1
    float L = 0.f, W = 0.f;
#pragma unroll
    for (int ch = 0; ch < NCH; ++ch) {
        L += pl[ch * (NB * NT) + r];
        W += pw[ch * (NB * NT) + r];
    }
    linv[r] = 1.f / L;
    out_w[r] = W / L;
}

// ---------------------------------------------------------------------------
// Kernel 4: normalizeE — streaming in-place: read row's bf16 E (4 KB, upper
// half), barrier, write full 8 KB f32 row = E * (1/L). One row per block-iter.
// ---------------------------------------------------------------------------
__launch_bounds__(256)
__global__ void normalizeE(const float* __restrict__ linv, float* __restrict__ out_att) {
    const int tid = threadIdx.x;
    for (int row = blockIdx.x; row < NB * NT; row += gridDim.x) {
        float* orow = out_att + (size_t)row * NT;
        const float li = linv[row];
        const bf16* erow = (const bf16*)orow + NT;
        const bf16x8 e = *(const bf16x8*)(erow + tid * 8);
        __syncthreads();  // all E reads done before any in-place overwrite
        f32x4 o0, o1;
#pragma unroll
        for (int i = 0; i < 4; ++i) {
            o0[i] = (float)e[i] * li;
            o1[i] = (float)e[4 + i] * li;
        }
        *(f32x4*)(orow + tid * 8)     = o0;
        *(f32x4*)(orow + tid * 8 + 4) = o1;
    }
}

// ---------------------------------------------------------------------------
extern "C" void kernel_launch(void* const* d_in, const int* in_sizes, int n_in,
                              void* d_out, int out_size, void* d_ws, size_t ws_size,
                              hipStream_t stream) {
    const float* x  = (const float*)d_in[0];
    const float* Wq = (const float*)d_in[1];
    const float* bq = (const float*)d_in[2];
    const float* Wk = (const float*)d_in[3];
    const float* bk = (const float*)d_in[4];
    const float* Wv = (const float*)d_in[5];
    const float* bv = (const float*)d_in[6];

    float* out_w   = (float*)d_out;            // [B,T,1] = 32768
    float* out_att = (float*)d_out + NB * NT;  // [B,T,T]

    char* ws = (char*)d_ws;
    bf16*  WT   = (bf16*)ws;                         // 262144 B
    float* V    = (float*)(ws + 262144);             // 131072 B
    bf16*  QK   = (bf16*)(ws + 393216);              // 16 MB
    float* pl   = (float*)(ws + 17170432);           // 512 KB
    float* pw   = (float*)(ws + 17694720);           // 512 KB
    float* linv = (float*)(ws + 18219008);           // 128 KB

    prep_wt<<<dim3(256), dim3(256), 0, stream>>>(Wq, Wk, WT);
    norm_proj<<<dim3((NB * NT) / 16), dim3(256), 0, stream>>>(x, Wv, bv, WT, bq, bk, QK, V);
    scoreE<<<dim3(NT / 64, NCH, NB), dim3(256), 0, stream>>>(QK, V, pl, pw, out_att);
    attn_reduce<<<dim3((NB * NT) / 256), dim3(256), 0, stream>>>(pl, pw, linv, out_w);
    normalizeE<<<dim3(2048), dim3(256), 0, stream>>>(linv, out_att);
}

// Round 10
// 193.495 us; speedup vs baseline: 1.0881x; 1.0881x over previous
//
#include <hip/hip_runtime.h>

// Problem constants (B=16, T=2048, D=512, A=128)
#define NB 16
#define NT 2048
#define ND 512
#define NA 128
#define EPSV 1e-6f
#define SCALE 0.08838834764831845f  // 128^-0.5
#define NCH 4        // s-chunks in attention
#define SCH 512      // s-chunk length

typedef __bf16 bf16;
typedef __bf16 bf16x4 __attribute__((ext_vector_type(4)));
typedef __bf16 bf16x8 __attribute__((ext_vector_type(8)));
typedef float f32x4 __attribute__((ext_vector_type(4)));

// ---------------------------------------------------------------------------
// Kernel 0: build W^T bf16 [256][512]  (rows 0..127 = Wq cols, 128..255 = Wk)
// ---------------------------------------------------------------------------
__global__ void prep_wt(const float* __restrict__ Wq, const float* __restrict__ Wk,
                        bf16* __restrict__ WT) {
    int n = blockIdx.x;
    const float* W = (n < NA) ? Wq : Wk;
    int col = n & (NA - 1);
    for (int k = threadIdx.x; k < ND; k += blockDim.x)
        WT[(size_t)n * ND + k] = (bf16)W[(size_t)k * NA + col];
}

// ---------------------------------------------------------------------------
// Kernel 1: fused norm + V + QK projection GEMM. 16 rows/block, grid 2048.
// ---------------------------------------------------------------------------
__launch_bounds__(256)
__global__ void norm_proj(const float* __restrict__ x, const float* __restrict__ Wv,
                          const float* __restrict__ bvp, const bf16* __restrict__ WT,
                          const float* __restrict__ bq, const float* __restrict__ bk,
                          bf16* __restrict__ QK, float* __restrict__ Vout) {
    __shared__ bf16 xn[16 * ND];  // 16 KB, XOR-swizzled rows
    const int tid = threadIdx.x;
    const int lane = tid & 63, wv = tid >> 6;
    const int row0 = blockIdx.x * 16;

    float wvv[8];
    float sumw = 0.f;
#pragma unroll
    for (int i = 0; i < 4; ++i) { wvv[i]     = Wv[lane * 4 + i];       sumw += wvv[i]; }
#pragma unroll
    for (int i = 0; i < 4; ++i) { wvv[4 + i] = Wv[256 + lane * 4 + i]; sumw += wvv[4 + i]; }
#pragma unroll
    for (int m = 1; m < 64; m <<= 1) sumw += __shfl_xor(sumw, m);
    const float bvs = bvp[0];

#pragma unroll
    for (int r = 0; r < 4; ++r) {
        const int lrow = wv * 4 + r;
        const int grow = row0 + lrow;
        const float* xr = x + (size_t)grow * ND;
        f32x4 a = *(const f32x4*)(xr + lane * 4);
        f32x4 b = *(const f32x4*)(xr + 256 + lane * 4);
        float s = 0.f, sq = 0.f, dw = 0.f;
#pragma unroll
        for (int i = 0; i < 4; ++i) { s += a[i]; sq += a[i] * a[i]; dw += a[i] * wvv[i]; }
#pragma unroll
        for (int i = 0; i < 4; ++i) { s += b[i]; sq += b[i] * b[i]; dw += b[i] * wvv[4 + i]; }
#pragma unroll
        for (int m = 1; m < 64; m <<= 1) {
            s  += __shfl_xor(s, m);
            sq += __shfl_xor(sq, m);
            dw += __shfl_xor(dw, m);
        }
        const float mu  = s * (1.f / 512.f);
        float var = (sq - 512.f * mu * mu) * (1.f / 511.f);
        var = fmaxf(var, 0.f);
        const float inv = 1.f / (sqrtf(var) + EPSV);
        if (lane == 0) Vout[grow] = (dw - mu * sumw) * inv + bvs;

        const int sw = (lrow & 7) << 4;
        bf16x4 v0, v1;
#pragma unroll
        for (int i = 0; i < 4; ++i) v0[i] = (bf16)((a[i] - mu) * inv);
#pragma unroll
        for (int i = 0; i < 4; ++i) v1[i] = (bf16)((b[i] - mu) * inv);
        *(bf16x4*)((char*)xn + lrow * 1024 + ((lane * 8) ^ sw))       = v0;
        *(bf16x4*)((char*)xn + lrow * 1024 + ((512 + lane * 8) ^ sw)) = v1;
    }
    __syncthreads();

    const int c = lane & 15, g = lane >> 4;
    const int asw = (c & 7) << 4;
    f32x4 acc[4];
#pragma unroll
    for (int i = 0; i < 4; ++i) acc[i] = f32x4{0.f, 0.f, 0.f, 0.f};

    for (int ks = 0; ks < 16; ++ks) {
        const bf16x8 af = *(const bf16x8*)((const char*)xn + c * 1024 +
                                           ((ks * 64 + g * 16) ^ asw));
#pragma unroll
        for (int i = 0; i < 4; ++i) {
            const int n = wv * 64 + i * 16 + c;
            const bf16x8 bfr = *(const bf16x8*)(WT + (size_t)n * ND + ks * 32 + g * 8);
            acc[i] = __builtin_amdgcn_mfma_f32_16x16x32_bf16(af, bfr, acc[i], 0, 0, 0);
        }
    }
#pragma unroll
    for (int i = 0; i < 4; ++i) {
        const int n = wv * 64 + i * 16 + c;
        const float bias = (n < NA) ? bq[n] : bk[n - NA];
#pragma unroll
        for (int j = 0; j < 4; ++j)
            QK[(size_t)(row0 + g * 4 + j) * 256 + n] = (bf16)(acc[i][j] + bias);
    }
}

// ---------------------------------------------------------------------------
// Kernel 2: pass1 — per-chunk sums l = sum(exp s), w = sum(exp s * V).
// R4 structure exactly (measured best).
// ---------------------------------------------------------------------------
__launch_bounds__(256)
__global__ void attn_pass1(const bf16* __restrict__ QK, const float* __restrict__ Vg,
                           float* __restrict__ pl, float* __restrict__ pw) {
    __shared__ bf16 Kt[64 * NA];  // 16 KB, XOR-swizzled
    const int tid = threadIdx.x;
    const int lane = tid & 63, wv = tid >> 6;
    const int b = blockIdx.z, t0 = blockIdx.x * 64, sc = blockIdx.y;
    const int c = lane & 15, g = lane >> 4;
    const int trow = t0 + wv * 16 + c;

    bf16x8 qf[4];
    const bf16* qrow = QK + (size_t)(b * NT + trow) * 256;
#pragma unroll
    for (int ks = 0; ks < 4; ++ks) qf[ks] = *(const bf16x8*)(qrow + ks * 32 + g * 8);

    const int srow = tid >> 4, scc = tid & 15;
    const bf16* kbase = QK + (size_t)(b * NT + sc * SCH + srow) * 256 + NA + scc * 8;
    bf16* kdst = (bf16*)((char*)Kt + srow * 256 + ((scc * 16) ^ ((srow & 7) << 4)));
    bf16x8 sreg[4];

#pragma unroll
    for (int i = 0; i < 4; ++i)
        sreg[i] = *(const bf16x8*)(kbase + (size_t)(i * 16) * 256);

    const float* vbase = Vg + b * NT + sc * SCH;
    float l_loc = 0.f, w_loc = 0.f;

    for (int tt = 0; tt < SCH / 64; ++tt) {
        __syncthreads();
#pragma unroll
        for (int i = 0; i < 4; ++i)
            *(bf16x8*)((char*)kdst + i * 16 * 256) = sreg[i];
        if (tt + 1 < SCH / 64) {
#pragma unroll
            for (int i = 0; i < 4; ++i)
                sreg[i] = *(const bf16x8*)(kbase + (size_t)((tt + 1) * 64 + i * 16) * 256);
        }
        __syncthreads();

#pragma unroll
        for (int ns = 0; ns < 4; ++ns) {
            f32x4 acc = f32x4{0.f, 0.f, 0.f, 0.f};
            const int rr = ns * 16 + c;
            const int rsw = (rr & 7) << 4;
#pragma unroll
            for (int ks = 0; ks < 4; ++ks) {
                const bf16x8 afr = *(const bf16x8*)((const char*)Kt + rr * 256 +
                                                    ((ks * 64 + g * 16) ^ rsw));
                acc = __builtin_amdgcn_mfma_f32_16x16x32_bf16(afr, qf[ks], acc, 0, 0, 0);
            }
            const f32x4 vv = *(const f32x4*)(vbase + tt * 64 + ns * 16 + g * 4);
#pragma unroll
            for (int jj = 0; jj < 4; ++jj) {
                const float p = __expf(acc[jj] * SCALE);
                l_loc += p;
                w_loc += p * vv[jj];
            }
        }
    }

#pragma unroll
    for (int mask = 16; mask <= 32; mask <<= 1) {
        l_loc += __shfl_xor(l_loc, mask);
        w_loc += __shfl_xor(w_loc, mask);
    }
    if (g == 0) {
        const int idx = sc * (NB * NT) + b * NT + trow;
        pl[idx] = l_loc;
        pw[idx] = w_loc;
    }
}

// ---------------------------------------------------------------------------
// Kernel 3: merge the 4 chunk-partials -> 1/l, out_w
// ---------------------------------------------------------------------------
__global__ void attn_reduce(const float* __restrict__ pl, const float* __restrict__ pw,
                            float* __restrict__ linv, float* __restrict__ out_w) {
    const int r = blockIdx.x * 256 + threadIdx.x;  // 0 .. NB*NT-1
    float L = 0.f, W = 0.f;
#pragma unroll
    for (int ch = 0; ch < NCH; ++ch) {
        L += pl[ch * (NB * NT) + r];
        W += pw[ch * (NB * NT) + r];
    }
    linv[r] = 1.f / L;
    out_w[r] = W / L;
}

// ---------------------------------------------------------------------------
// Kernel 4: pass2 — recompute scores, write normalized w_att.
// R4 structure; single change: NONTEMPORAL f32x4 stores (bypass L2 retention
// for the 268 MB one-shot stream, keep L2 for K/Q reuse).
// ---------------------------------------------------------------------------
__launch_bounds__(256)
__global__ void attn_pass2(const bf16* __restrict__ QK, const float* __restrict__ linv,
                           float* __restrict__ out_att) {
    __shared__ bf16 Kt[64 * NA];
    const int tid = threadIdx.x;
    const int lane = tid & 63, wv = tid >> 6;
    const int b = blockIdx.z, t0 = blockIdx.x * 64, sc = blockIdx.y;
    const int c = lane & 15, g = lane >> 4;
    const int trow = t0 + wv * 16 + c;

    bf16x8 qf[4];
    const bf16* qrow = QK + (size_t)(b * NT + trow) * 256;
#pragma unroll
    for (int ks = 0; ks < 4; ++ks) qf[ks] = *(const bf16x8*)(qrow + ks * 32 + g * 8);

    const float lrow = linv[b * NT + trow];
    float* orow = out_att + (size_t)(b * NT + trow) * NT;

    const int srow = tid >> 4, scc = tid & 15;
    const bf16* kbase = QK + (size_t)(b * NT + sc * SCH + srow) * 256 + NA + scc * 8;
    bf16* kdst = (bf16*)((char*)Kt + srow * 256 + ((scc * 16) ^ ((srow & 7) << 4)));
    bf16x8 sreg[4];

#pragma unroll
    for (int i = 0; i < 4; ++i)
        sreg[i] = *(const bf16x8*)(kbase + (size_t)(i * 16) * 256);

    for (int tt = 0; tt < SCH / 64; ++tt) {
        __syncthreads();
#pragma unroll
        for (int i = 0; i < 4; ++i)
            *(bf16x8*)((char*)kdst + i * 16 * 256) = sreg[i];
        if (tt + 1 < SCH / 64) {
#pragma unroll
            for (int i = 0; i < 4; ++i)
                sreg[i] = *(const bf16x8*)(kbase + (size_t)((tt + 1) * 64 + i * 16) * 256);
        }
        __syncthreads();

        const int s0 = sc * SCH + tt * 64;
#pragma unroll
        for (int ns = 0; ns < 4; ++ns) {
            f32x4 acc = f32x4{0.f, 0.f, 0.f, 0.f};
            const int rr = ns * 16 + c;
            const int rsw = (rr & 7) << 4;
#pragma unroll
            for (int ks = 0; ks < 4; ++ks) {
                const bf16x8 afr = *(const bf16x8*)((const char*)Kt + rr * 256 +
                                                    ((ks * 64 + g * 16) ^ rsw));
                acc = __builtin_amdgcn_mfma_f32_16x16x32_bf16(afr, qf[ks], acc, 0, 0, 0);
            }
            f32x4 w;
#pragma unroll
            for (int jj = 0; jj < 4; ++jj)
                w[jj] = __expf(acc[jj] * SCALE) * lrow;
            __builtin_nontemporal_store(w, (f32x4*)(orow + s0 + ns * 16 + g * 4));
        }
    }
}

// ---------------------------------------------------------------------------
extern "C" void kernel_launch(void* const* d_in, const int* in_sizes, int n_in,
                              void* d_out, int out_size, void* d_ws, size_t ws_size,
                              hipStream_t stream) {
    const float* x  = (const float*)d_in[0];
    const float* Wq = (const float*)d_in[1];
    const float* bq = (const float*)d_in[2];
    const float* Wk = (const float*)d_in[3];
    const float* bk = (const float*)d_in[4];
    const float* Wv = (const float*)d_in[5];
    const float* bv = (const float*)d_in[6];

    float* out_w   = (float*)d_out;            // [B,T,1] = 32768
    float* out_att = (float*)d_out + NB * NT;  // [B,T,T]

    char* ws = (char*)d_ws;
    bf16*  WT   = (bf16*)ws;                         // 262144 B
    float* V    = (float*)(ws + 262144);             // 131072 B
    bf16*  QK   = (bf16*)(ws + 393216);              // 16 MB
    float* pl   = (float*)(ws + 17170432);           // 512 KB
    float* pw   = (float*)(ws + 17694720);           // 512 KB
    float* linv = (float*)(ws + 18219008);           // 128 KB

    prep_wt<<<dim3(256), dim3(256), 0, stream>>>(Wq, Wk, WT);
    norm_proj<<<dim3((NB * NT) / 16), dim3(256), 0, stream>>>(x, Wv, bv, WT, bq, bk, QK, V);
    attn_pass1<<<dim3(NT / 64, NCH, NB), dim3(256), 0, stream>>>(QK, V, pl, pw);
    attn_reduce<<<dim3((NB * NT) / 256), dim3(256), 0, stream>>>(pl, pw, linv, out_w);
    attn_pass2<<<dim3(NT / 64, NCH, NB), dim3(256), 0, stream>>>(QK, linv, out_att);
}

// Round 11
// 174.900 us; speedup vs baseline: 1.2038x; 1.1063x over previous
//
#include <hip/hip_runtime.h>

// Problem constants (B=16, T=2048, D=512, A=128)
#define NB 16
#define NT 2048
#define ND 512
#define NA 128
#define EPSV 1e-6f
#define SCALE 0.08838834764831845f  // 128^-0.5
#define NCH 4        // s-chunks in attention
#define SCH 512      // s-chunk length

typedef __bf16 bf16;
typedef __bf16 bf16x4 __attribute__((ext_vector_type(4)));
typedef __bf16 bf16x8 __attribute__((ext_vector_type(8)));
typedef float f32x4 __attribute__((ext_vector_type(4)));

// ---------------------------------------------------------------------------
// Kernel 0: build W^T bf16 [256][512]  (rows 0..127 = Wq cols, 128..255 = Wk)
// ---------------------------------------------------------------------------
__global__ void prep_wt(const float* __restrict__ Wq, const float* __restrict__ Wk,
                        bf16* __restrict__ WT) {
    int n = blockIdx.x;
    const float* W = (n < NA) ? Wq : Wk;
    int col = n & (NA - 1);
    for (int k = threadIdx.x; k < ND; k += blockDim.x)
        WT[(size_t)n * ND + k] = (bf16)W[(size_t)k * NA + col];
}

// ---------------------------------------------------------------------------
// Kernel 1: fused norm + V + QK projection GEMM. 16 rows/block, grid 2048.
// ---------------------------------------------------------------------------
__launch_bounds__(256)
__global__ void norm_proj(const float* __restrict__ x, const float* __restrict__ Wv,
                          const float* __restrict__ bvp, const bf16* __restrict__ WT,
                          const float* __restrict__ bq, const float* __restrict__ bk,
                          bf16* __restrict__ QK, float* __restrict__ Vout) {
    __shared__ bf16 xn[16 * ND];  // 16 KB, XOR-swizzled rows
    const int tid = threadIdx.x;
    const int lane = tid & 63, wv = tid >> 6;
    const int row0 = blockIdx.x * 16;

    float wvv[8];
    float sumw = 0.f;
#pragma unroll
    for (int i = 0; i < 4; ++i) { wvv[i]     = Wv[lane * 4 + i];       sumw += wvv[i]; }
#pragma unroll
    for (int i = 0; i < 4; ++i) { wvv[4 + i] = Wv[256 + lane * 4 + i]; sumw += wvv[4 + i]; }
#pragma unroll
    for (int m = 1; m < 64; m <<= 1) sumw += __shfl_xor(sumw, m);
    const float bvs = bvp[0];

#pragma unroll
    for (int r = 0; r < 4; ++r) {
        const int lrow = wv * 4 + r;
        const int grow = row0 + lrow;
        const float* xr = x + (size_t)grow * ND;
        f32x4 a = *(const f32x4*)(xr + lane * 4);
        f32x4 b = *(const f32x4*)(xr + 256 + lane * 4);
        float s = 0.f, sq = 0.f, dw = 0.f;
#pragma unroll
        for (int i = 0; i < 4; ++i) { s += a[i]; sq += a[i] * a[i]; dw += a[i] * wvv[i]; }
#pragma unroll
        for (int i = 0; i < 4; ++i) { s += b[i]; sq += b[i] * b[i]; dw += b[i] * wvv[4 + i]; }
#pragma unroll
        for (int m = 1; m < 64; m <<= 1) {
            s  += __shfl_xor(s, m);
            sq += __shfl_xor(sq, m);
            dw += __shfl_xor(dw, m);
        }
        const float mu  = s * (1.f / 512.f);
        float var = (sq - 512.f * mu * mu) * (1.f / 511.f);
        var = fmaxf(var, 0.f);
        const float inv = 1.f / (sqrtf(var) + EPSV);
        if (lane == 0) Vout[grow] = (dw - mu * sumw) * inv + bvs;

        const int sw = (lrow & 7) << 4;
        bf16x4 v0, v1;
#pragma unroll
        for (int i = 0; i < 4; ++i) v0[i] = (bf16)((a[i] - mu) * inv);
#pragma unroll
        for (int i = 0; i < 4; ++i) v1[i] = (bf16)((b[i] - mu) * inv);
        *(bf16x4*)((char*)xn + lrow * 1024 + ((lane * 8) ^ sw))       = v0;
        *(bf16x4*)((char*)xn + lrow * 1024 + ((512 + lane * 8) ^ sw)) = v1;
    }
    __syncthreads();

    const int c = lane & 15, g = lane >> 4;
    const int asw = (c & 7) << 4;
    f32x4 acc[4];
#pragma unroll
    for (int i = 0; i < 4; ++i) acc[i] = f32x4{0.f, 0.f, 0.f, 0.f};

    for (int ks = 0; ks < 16; ++ks) {
        const bf16x8 af = *(const bf16x8*)((const char*)xn + c * 1024 +
                                           ((ks * 64 + g * 16) ^ asw));
#pragma unroll
        for (int i = 0; i < 4; ++i) {
            const int n = wv * 64 + i * 16 + c;
            const bf16x8 bfr = *(const bf16x8*)(WT + (size_t)n * ND + ks * 32 + g * 8);
            acc[i] = __builtin_amdgcn_mfma_f32_16x16x32_bf16(af, bfr, acc[i], 0, 0, 0);
        }
    }
#pragma unroll
    for (int i = 0; i < 4; ++i) {
        const int n = wv * 64 + i * 16 + c;
        const float bias = (n < NA) ? bq[n] : bk[n - NA];
#pragma unroll
        for (int j = 0; j < 4; ++j)
            QK[(size_t)(row0 + g * 4 + j) * 256 + n] = (bf16)(acc[i][j] + bias);
    }
}

// ---------------------------------------------------------------------------
// Kernel 2: pass1 — per-chunk sums l = sum(exp s), w = sum(exp s * V).
// R4 structure; loop reordered to issue-early/write-late so the pre-barrier
// vmcnt(0) drain lands AFTER compute has covered the prefetch latency.
// ---------------------------------------------------------------------------
__launch_bounds__(256)
__global__ void attn_pass1(const bf16* __restrict__ QK, const float* __restrict__ Vg,
                           float* __restrict__ pl, float* __restrict__ pw) {
    __shared__ bf16 Kt[64 * NA];  // 16 KB, XOR-swizzled
    const int tid = threadIdx.x;
    const int lane = tid & 63, wv = tid >> 6;
    const int b = blockIdx.z, t0 = blockIdx.x * 64, sc = blockIdx.y;
    const int c = lane & 15, g = lane >> 4;
    const int trow = t0 + wv * 16 + c;

    bf16x8 qf[4];
    const bf16* qrow = QK + (size_t)(b * NT + trow) * 256;
#pragma unroll
    for (int ks = 0; ks < 4; ++ks) qf[ks] = *(const bf16x8*)(qrow + ks * 32 + g * 8);

    const int srow = tid >> 4, scc = tid & 15;
    const bf16* kbase = QK + (size_t)(b * NT + sc * SCH + srow) * 256 + NA + scc * 8;
    bf16* kdst = (bf16*)((char*)Kt + srow * 256 + ((scc * 16) ^ ((srow & 7) << 4)));
    bf16x8 sreg[4];

    // prologue: stage tile 0
#pragma unroll
    for (int i = 0; i < 4; ++i)
        sreg[i] = *(const bf16x8*)(kbase + (size_t)(i * 16) * 256);
#pragma unroll
    for (int i = 0; i < 4; ++i)
        *(bf16x8*)((char*)kdst + i * 16 * 256) = sreg[i];
    __syncthreads();

    const float* vbase = Vg + b * NT + sc * SCH;
    float l_loc = 0.f, w_loc = 0.f;

    for (int tt = 0; tt < SCH / 64; ++tt) {
        if (tt + 1 < SCH / 64) {  // issue next-tile loads BEFORE compute
#pragma unroll
            for (int i = 0; i < 4; ++i)
                sreg[i] = *(const bf16x8*)(kbase + (size_t)((tt + 1) * 64 + i * 16) * 256);
        }

#pragma unroll
        for (int ns = 0; ns < 4; ++ns) {
            f32x4 acc = f32x4{0.f, 0.f, 0.f, 0.f};
            const int rr = ns * 16 + c;
            const int rsw = (rr & 7) << 4;
#pragma unroll
            for (int ks = 0; ks < 4; ++ks) {
                const bf16x8 afr = *(const bf16x8*)((const char*)Kt + rr * 256 +
                                                    ((ks * 64 + g * 16) ^ rsw));
                acc = __builtin_amdgcn_mfma_f32_16x16x32_bf16(afr, qf[ks], acc, 0, 0, 0);
            }
            const f32x4 vv = *(const f32x4*)(vbase + tt * 64 + ns * 16 + g * 4);
#pragma unroll
            for (int jj = 0; jj < 4; ++jj) {
                const float p = __expf(acc[jj] * SCALE);
                l_loc += p;
                w_loc += p * vv[jj];
            }
        }

        if (tt + 1 < SCH / 64) {
            __syncthreads();  // waves done reading Kt; vmcnt drain covered by compute
#pragma unroll
            for (int i = 0; i < 4; ++i)
                *(bf16x8*)((char*)kdst + i * 16 * 256) = sreg[i];
            __syncthreads();  // Kt visible
        }
    }

#pragma unroll
    for (int mask = 16; mask <= 32; mask <<= 1) {
        l_loc += __shfl_xor(l_loc, mask);
        w_loc += __shfl_xor(w_loc, mask);
    }
    if (g == 0) {
        const int idx = sc * (NB * NT) + b * NT + trow;
        pl[idx] = l_loc;
        pw[idx] = w_loc;
    }
}

// ---------------------------------------------------------------------------
// Kernel 3: merge the 4 chunk-partials -> 1/l, out_w
// ---------------------------------------------------------------------------
__global__ void attn_reduce(const float* __restrict__ pl, const float* __restrict__ pw,
                            float* __restrict__ linv, float* __restrict__ out_w) {
    const int r = blockIdx.x * 256 + threadIdx.x;  // 0 .. NB*NT-1
    float L = 0.f, W = 0.f;
#pragma unroll
    for (int ch = 0; ch < NCH; ++ch) {
        L += pl[ch * (NB * NT) + r];
        W += pw[ch * (NB * NT) + r];
    }
    linv[r] = 1.f / L;
    out_w[r] = W / L;
}

// ---------------------------------------------------------------------------
// Kernel 4: pass2 — recompute scores, write normalized w_att.
// Same issue-early/write-late reorder; plain f32x4 stores (NT reverted).
// ---------------------------------------------------------------------------
__launch_bounds__(256)
__global__ void attn_pass2(const bf16* __restrict__ QK, const float* __restrict__ linv,
                           float* __restrict__ out_att) {
    __shared__ bf16 Kt[64 * NA];
    const int tid = threadIdx.x;
    const int lane = tid & 63, wv = tid >> 6;
    const int b = blockIdx.z, t0 = blockIdx.x * 64, sc = blockIdx.y;
    const int c = lane & 15, g = lane >> 4;
    const int trow = t0 + wv * 16 + c;

    bf16x8 qf[4];
    const bf16* qrow = QK + (size_t)(b * NT + trow) * 256;
#pragma unroll
    for (int ks = 0; ks < 4; ++ks) qf[ks] = *(const bf16x8*)(qrow + ks * 32 + g * 8);

    const float lrow = linv[b * NT + trow];
    float* orow = out_att + (size_t)(b * NT + trow) * NT;

    const int srow = tid >> 4, scc = tid & 15;
    const bf16* kbase = QK + (size_t)(b * NT + sc * SCH + srow) * 256 + NA + scc * 8;
    bf16* kdst = (bf16*)((char*)Kt + srow * 256 + ((scc * 16) ^ ((srow & 7) << 4)));
    bf16x8 sreg[4];

#pragma unroll
    for (int i = 0; i < 4; ++i)
        sreg[i] = *(const bf16x8*)(kbase + (size_t)(i * 16) * 256);
#pragma unroll
    for (int i = 0; i < 4; ++i)
        *(bf16x8*)((char*)kdst + i * 16 * 256) = sreg[i];
    __syncthreads();

    for (int tt = 0; tt < SCH / 64; ++tt) {
        if (tt + 1 < SCH / 64) {  // issue next-tile loads BEFORE compute
#pragma unroll
            for (int i = 0; i < 4; ++i)
                sreg[i] = *(const bf16x8*)(kbase + (size_t)((tt + 1) * 64 + i * 16) * 256);
        }

        const int s0 = sc * SCH + tt * 64;
#pragma unroll
        for (int ns = 0; ns < 4; ++ns) {
            f32x4 acc = f32x4{0.f, 0.f, 0.f, 0.f};
            const int rr = ns * 16 + c;
            const int rsw = (rr & 7) << 4;
#pragma unroll
            for (int ks = 0; ks < 4; ++ks) {
                const bf16x8 afr = *(const bf16x8*)((const char*)Kt + rr * 256 +
                                                    ((ks * 64 + g * 16) ^ rsw));
                acc = __builtin_amdgcn_mfma_f32_16x16x32_bf16(afr, qf[ks], acc, 0, 0, 0);
            }
            f32x4 w;
#pragma unroll
            for (int jj = 0; jj < 4; ++jj)
                w[jj] = __expf(acc[jj] * SCALE) * lrow;
            *(f32x4*)(orow + s0 + ns * 16 + g * 4) = w;
        }

        if (tt + 1 < SCH / 64) {
            __syncthreads();
#pragma unroll
            for (int i = 0; i < 4; ++i)
                *(bf16x8*)((char*)kdst + i * 16 * 256) = sreg[i];
            __syncthreads();
        }
    }
}

// ---------------------------------------------------------------------------
extern "C" void kernel_launch(void* const* d_in, const int* in_sizes, int n_in,
                              void* d_out, int out_size, void* d_ws, size_t ws_size,
                              hipStream_t stream) {
    const float* x  = (const float*)d_in[0];
    const float* Wq = (const float*)d_in[1];
    const float* bq = (const float*)d_in[2];
    const float* Wk = (const float*)d_in[3];
    const float* bk = (const float*)d_in[4];
    const float* Wv = (const float*)d_in[5];
    const float* bv = (const float*)d_in[6];

    float* out_w   = (float*)d_out;            // [B,T,1] = 32768
    float* out_att = (float*)d_out + NB * NT;  // [B,T,T]

    char* ws = (char*)d_ws;
    bf16*  WT   = (bf16*)ws;                         // 262144 B
    float* V    = (float*)(ws + 262144);             // 131072 B
    bf16*  QK   = (bf16*)(ws + 393216);              // 16 MB
    float* pl   = (float*)(ws + 17170432);           // 512 KB
    float* pw   = (float*)(ws + 17694720);           // 512 KB
    float* linv = (float*)(ws + 18219008);           // 128 KB

    prep_wt<<<dim3(256), dim3(256), 0, stream>>>(Wq, Wk, WT);
    norm_proj<<<dim3((NB * NT) / 16), dim3(256), 0, stream>>>(x, Wv, bv, WT, bq, bk, QK, V);
    attn_pass1<<<dim3(NT / 64, NCH, NB), dim3(256), 0, stream>>>(QK, V, pl, pw);
    attn_reduce<<<dim3((NB * NT) / 256), dim3(256), 0, stream>>>(pl, pw, linv, out_w);
    attn_pass2<<<dim3(NT / 64, NCH, NB), dim3(256), 0, stream>>>(QK, linv, out_att);
}